// Round 1
// baseline (10613.695 us; speedup 1.0000x reference)
//
#include <hip/hip_runtime.h>
#include <math.h>

// Problem constants (fixed by setup_inputs):
//   B=4, T=1024, D=512, G=4*D=2048, V=32000
// Workspace layout (needs >= 56MB + 8KB):
//   [0,8M)    x        [4096,512]  f32
//   [8M,40M)  xg       [4096,2048] f32   (reused for both layers)
//   [40M,48M) h1       [4096,512]  f32
//   [48M,56M) h2       [4096,512]  f32
//   [56M,+8K) flags0/flags1 (64 u32 each, zeroed per launch)

#define TSEQ 1024
#define DIM  512
#define GDIM 2048
#define NWG  64

// ---------------------------------------------------------------------------
// Embedding lookup with shift-right: x[b,t,:] = embed[ t==0 ? 0 : tokens[b,t-1] ]
// ---------------------------------------------------------------------------
__global__ void embed_kernel(const int* __restrict__ tokens,
                             const float* __restrict__ embed,
                             float* __restrict__ x)
{
    const int row = blockIdx.x;          // b*T + t
    const int b = row >> 10;
    const int t = row & 1023;
    const int tok = (t == 0) ? 0 : tokens[b * TSEQ + t - 1];
    const float4* src = (const float4*)(embed + (size_t)tok * DIM);
    float4* dst = (float4*)(x + (size_t)row * DIM);
    dst[threadIdx.x] = src[threadIdx.x];   // 128 threads * float4 = 512 floats
}

// ---------------------------------------------------------------------------
// fp32 GEMM with bias: C[M,N] = A[M,K] @ B[K,N] + bias[N]
// 128x128 tile, BK=16, 256 threads, 8x8 micro-tile. M%128==0, N%128==0, K%16==0.
// ---------------------------------------------------------------------------
__global__ __launch_bounds__(256) void gemm_bias_f32(
    const float* __restrict__ A, const float* __restrict__ Bm,
    const float* __restrict__ bias, float* __restrict__ C,
    int M, int N, int K)
{
    constexpr int BK = 16;
    __shared__ float As[BK][128 + 4];   // stored transposed: As[k][m]
    __shared__ float Bs[BK][128 + 4];

    const int tid = threadIdx.x;
    const int m0 = blockIdx.y * 128;
    const int n0 = blockIdx.x * 128;
    const int tm = (tid >> 4) << 3;     // 0..120
    const int tn = (tid & 15) << 3;     // 0..120

    const int a_r = tid >> 2;           // 0..63
    const int a_c = (tid & 3) << 2;     // 0,4,8,12
    const int b_r = tid >> 5;           // 0..7
    const int b_c = (tid & 31) << 2;    // 0..124

    float acc[8][8] = {};

    for (int k0 = 0; k0 < K; k0 += BK) {
        // global loads (issue before barrier so they overlap previous compute)
        const float4 av0 = *(const float4*)&A[(size_t)(m0 + a_r) * K + k0 + a_c];
        const float4 av1 = *(const float4*)&A[(size_t)(m0 + a_r + 64) * K + k0 + a_c];
        const float4 bv0 = *(const float4*)&Bm[(size_t)(k0 + b_r) * N + n0 + b_c];
        const float4 bv1 = *(const float4*)&Bm[(size_t)(k0 + b_r + 8) * N + n0 + b_c];
        __syncthreads();   // previous iteration's LDS reads done
        As[a_c + 0][a_r] = av0.x;  As[a_c + 1][a_r] = av0.y;
        As[a_c + 2][a_r] = av0.z;  As[a_c + 3][a_r] = av0.w;
        As[a_c + 0][a_r + 64] = av1.x;  As[a_c + 1][a_r + 64] = av1.y;
        As[a_c + 2][a_r + 64] = av1.z;  As[a_c + 3][a_r + 64] = av1.w;
        *(float4*)&Bs[b_r][b_c] = bv0;
        *(float4*)&Bs[b_r + 8][b_c] = bv1;
        __syncthreads();

        #pragma unroll
        for (int kk = 0; kk < BK; ++kk) {
            float a[8], bf[8];
            *(float4*)&a[0]  = *(const float4*)&As[kk][tm];
            *(float4*)&a[4]  = *(const float4*)&As[kk][tm + 4];
            *(float4*)&bf[0] = *(const float4*)&Bs[kk][tn];
            *(float4*)&bf[4] = *(const float4*)&Bs[kk][tn + 4];
            #pragma unroll
            for (int i = 0; i < 8; ++i)
                #pragma unroll
                for (int jx = 0; jx < 8; ++jx)
                    acc[i][jx] += a[i] * bf[jx];
        }
    }

    float bv[8];
    #pragma unroll
    for (int jx = 0; jx < 8; ++jx) bv[jx] = bias[n0 + tn + jx];

    #pragma unroll
    for (int i = 0; i < 8; ++i) {
        float* crow = C + (size_t)(m0 + tm + i) * N + (n0 + tn);
        float4 o0, o1;
        o0.x = acc[i][0] + bv[0]; o0.y = acc[i][1] + bv[1];
        o0.z = acc[i][2] + bv[2]; o0.w = acc[i][3] + bv[3];
        o1.x = acc[i][4] + bv[4]; o1.y = acc[i][5] + bv[5];
        o1.z = acc[i][6] + bv[6]; o1.w = acc[i][7] + bv[7];
        *(float4*)&crow[0] = o0;
        *(float4*)&crow[4] = o1;
    }
}

// ---------------------------------------------------------------------------
// Persistent LSTM layer: 64 WGs x 512 threads. WG k owns h-dims [8k, 8k+8).
// Wh slice (512 x 32 gate cols) lives in registers (32 VGPR/thread).
// Cross-WG h exchange via agent-scope relaxed atomics (sc1: bypasses the
// non-coherent per-XCD L2s) + per-WG monotonic flags. c-state is WG-private.
//   xg:  [B*T, 2048]  precomputed x@Wx + b
//   hs:  [B*T, 512]   output (h for every t)
// ---------------------------------------------------------------------------
__global__ __launch_bounds__(512, 1) void lstm_layer_kernel(
    const float* __restrict__ xg, const float* __restrict__ Wh,
    float* __restrict__ hs, unsigned* __restrict__ flags)
{
    const int wg    = blockIdx.x;     // 0..63
    const int tid   = threadIdx.x;    // 0..511
    const int dbase = wg * 8;

    __shared__ float h_lds[4][DIM];       // h_{t-1}, all 4 batch rows
    __shared__ float part[16][4][32];     // partial dots [s][b][j]
    __shared__ float gate_lds[4][32];     // final gate pre-activations

    const int j = tid & 31;               // gate-column index within slice
    const int s = tid >> 5;               // row-chunk 0..15 (rows s*32..s*32+31)
    // global gate column: j = q*8+dd -> col = q*512 + dbase + dd
    const int wcol = (j >> 3) * DIM + dbase + (j & 7);

    // Wh slice -> registers (one-time, 64KB/WG total)
    float w[32];
    #pragma unroll
    for (int r = 0; r < 32; ++r)
        w[r] = Wh[(size_t)(s * 32 + r) * GDIM + wcol];

    float c_reg = 0.f;                    // c-state for tid<32 (b=tid>>3, d=dbase+(tid&7))

    for (int t = 0; t < TSEQ; ++t) {
        // prefetch this step's xg contribution (combine threads only; for
        // tid<128, s doubles as the batch index and wcol as the gate column)
        float xg_val = 0.f;
        if (tid < 128)
            xg_val = xg[((size_t)s * TSEQ + t) * GDIM + wcol];

        if (t > 0) {
            if (tid < NWG) {
                while (__hip_atomic_load(&flags[tid], __ATOMIC_RELAXED,
                                         __HIP_MEMORY_SCOPE_AGENT) < (unsigned)t) { }
            }
            __syncthreads();
            // stage h_{t-1}: 4 coalesced rows, L1/L2-bypassing loads
            #pragma unroll
            for (int b = 0; b < 4; ++b)
                h_lds[b][tid] = __hip_atomic_load(
                    &hs[((size_t)b * TSEQ + (t - 1)) * DIM + tid],
                    __ATOMIC_RELAXED, __HIP_MEMORY_SCOPE_AGENT);
        } else {
            #pragma unroll
            for (int b = 0; b < 4; ++b) h_lds[b][tid] = 0.f;
        }
        __syncthreads();

        // MAC: rows [s*32, s*32+32) x 4 batches; weights in registers,
        // h reads are wave-broadcast ds_read_b128.
        const int r0 = s * 32;
        float a0 = 0.f, a1 = 0.f, a2 = 0.f, a3 = 0.f;
        const float4* h0p = (const float4*)&h_lds[0][r0];
        const float4* h1p = (const float4*)&h_lds[1][r0];
        const float4* h2p = (const float4*)&h_lds[2][r0];
        const float4* h3p = (const float4*)&h_lds[3][r0];
        #pragma unroll
        for (int r4 = 0; r4 < 8; ++r4) {
            const float4 v0 = h0p[r4], v1 = h1p[r4], v2 = h2p[r4], v3 = h3p[r4];
            a0 += v0.x * w[r4*4+0] + v0.y * w[r4*4+1] + v0.z * w[r4*4+2] + v0.w * w[r4*4+3];
            a1 += v1.x * w[r4*4+0] + v1.y * w[r4*4+1] + v1.z * w[r4*4+2] + v1.w * w[r4*4+3];
            a2 += v2.x * w[r4*4+0] + v2.y * w[r4*4+1] + v2.z * w[r4*4+2] + v2.w * w[r4*4+3];
            a3 += v3.x * w[r4*4+0] + v3.y * w[r4*4+1] + v3.z * w[r4*4+2] + v3.w * w[r4*4+3];
        }
        part[s][0][j] = a0; part[s][1][j] = a1;
        part[s][2][j] = a2; part[s][3][j] = a3;
        __syncthreads();

        // combine 16 partials + xg (tid<128: b=s, col=j)
        if (tid < 128) {
            float sum = xg_val;
            #pragma unroll
            for (int s2 = 0; s2 < 16; ++s2) sum += part[s2][s][j];
            gate_lds[s][j] = sum;
        }
        __syncthreads();

        // gate math + h/c update (tid<32: b=tid>>3, dd=tid&7)
        if (tid < 32) {
            const int ub = tid >> 3, ud = tid & 7;
            const float iv = gate_lds[ub][ 0 + ud];
            const float fv = gate_lds[ub][ 8 + ud];
            const float gv = gate_lds[ub][16 + ud];
            const float ov = gate_lds[ub][24 + ud];
            const float ig = 1.f / (1.f + expf(-iv));
            const float fg = 1.f / (1.f + expf(-fv));
            const float og = 1.f / (1.f + expf(-ov));
            c_reg = fg * c_reg + ig * tanhf(gv);
            const float hval = og * tanhf(c_reg);
            __hip_atomic_store(&hs[((size_t)ub * TSEQ + t) * DIM + dbase + ud], hval,
                               __ATOMIC_RELAXED, __HIP_MEMORY_SCOPE_AGENT);
        }
        // __syncthreads drains vmcnt (h stores complete at coherence point)
        // before the flag release.
        __syncthreads();
        if (tid == 0)
            __hip_atomic_store(&flags[wg], (unsigned)(t + 1),
                               __ATOMIC_RELAXED, __HIP_MEMORY_SCOPE_AGENT);
    }
}

// ---------------------------------------------------------------------------
extern "C" void kernel_launch(void* const* d_in, const int* in_sizes, int n_in,
                              void* d_out, int out_size, void* d_ws, size_t ws_size,
                              hipStream_t stream)
{
    const int*   tokens = (const int*)d_in[0];
    const float* embed  = (const float*)d_in[1];
    const float* Wx0    = (const float*)d_in[2];
    const float* Wh0    = (const float*)d_in[3];
    const float* b0     = (const float*)d_in[4];
    const float* Wx1    = (const float*)d_in[5];
    const float* Wh1    = (const float*)d_in[6];
    const float* b1     = (const float*)d_in[7];
    const float* Wout   = (const float*)d_in[8];
    const float* bout   = (const float*)d_in[9];
    float* out = (float*)d_out;

    char* ws = (char*)d_ws;
    float*    x      = (float*)(ws);
    float*    xg     = (float*)(ws + (size_t)( 8u << 20));
    float*    h1     = (float*)(ws + (size_t)(40u << 20));
    float*    h2     = (float*)(ws + (size_t)(48u << 20));
    unsigned* flags0 = (unsigned*)(ws + (size_t)(56u << 20));
    unsigned* flags1 = flags0 + 1024;

    // flags must start at 0 every launch (monotonic within a launch)
    hipMemsetAsync(flags0, 0, 8192, stream);

    embed_kernel<<<dim3(4096), dim3(128), 0, stream>>>(tokens, embed, x);

    gemm_bias_f32<<<dim3(16, 32), dim3(256), 0, stream>>>(x, Wx0, b0, xg, 4096, 2048, 512);
    lstm_layer_kernel<<<dim3(NWG), dim3(512), 0, stream>>>(xg, Wh0, h1, flags0);

    gemm_bias_f32<<<dim3(16, 32), dim3(256), 0, stream>>>(h1, Wx1, b1, xg, 4096, 2048, 512);
    lstm_layer_kernel<<<dim3(NWG), dim3(512), 0, stream>>>(xg, Wh1, h2, flags1);

    gemm_bias_f32<<<dim3(250, 32), dim3(256), 0, stream>>>(h2, Wout, bout, out, 4096, 32000, 512);
}

// Round 2
// 4921.596 us; speedup vs baseline: 2.1566x; 2.1566x over previous
//
#include <hip/hip_runtime.h>
#include <math.h>

// Problem constants: B=4, T=1024, D=512, G=4*D=2048, V=32000
// Workspace layout (56 MB, same footprint as round 1):
//   [0,8M)    x / hs2   [4096,512] f32  (x dead after xg1 GEMM; reused as hs2)
//   [8M,40M)  xg1       [4096,2048] f32
//   [40M,48M) h1c       [T][512][4] f32  sentinel-polled comm buffer, layer-1 h
//   [48M,56M) h2c       [T][512][4] f32  sentinel-polled comm buffer, layer-2 h

#define TSEQ 1024
#define DIM  512
#define GDIM 2048
#define SENT 0x7F7F7F7Fu   // memset pattern; == 3.39e38f, unreachable by h=sig*tanh

typedef unsigned uint4v __attribute__((ext_vector_type(4)));
typedef float    f4v    __attribute__((ext_vector_type(4)));

// Agent-scope (sc1: bypasses non-coherent per-XCD L2s) 16B poll load.
__device__ __forceinline__ uint4v poll_load16(const unsigned* p) {
    uint4v v;
    asm volatile("global_load_dwordx4 %0, %1, off sc1\n\t"
                 "s_waitcnt vmcnt(0)"
                 : "=v"(v) : "v"(p) : "memory");
    return v;
}

// ---------------------------------------------------------------------------
// Embedding lookup with shift-right
// ---------------------------------------------------------------------------
__global__ void embed_kernel(const int* __restrict__ tokens,
                             const float* __restrict__ embed,
                             float* __restrict__ x)
{
    const int row = blockIdx.x;          // b*T + t
    const int b = row >> 10;
    const int t = row & 1023;
    const int tok = (t == 0) ? 0 : tokens[b * TSEQ + t - 1];
    const float4* src = (const float4*)(embed + (size_t)tok * DIM);
    float4* dst = (float4*)(x + (size_t)row * DIM);
    dst[threadIdx.x] = src[threadIdx.x];
}

// ---------------------------------------------------------------------------
// fp32 GEMM with bias: C[M,N] = A[M,K] @ B[K,N] + bias[N]   (unchanged, passed)
// ---------------------------------------------------------------------------
__global__ __launch_bounds__(256) void gemm_bias_f32(
    const float* __restrict__ A, const float* __restrict__ Bm,
    const float* __restrict__ bias, float* __restrict__ C,
    int M, int N, int K)
{
    constexpr int BK = 16;
    __shared__ float As[BK][128 + 4];
    __shared__ float Bs[BK][128 + 4];

    const int tid = threadIdx.x;
    const int m0 = blockIdx.y * 128;
    const int n0 = blockIdx.x * 128;
    const int tm = (tid >> 4) << 3;
    const int tn = (tid & 15) << 3;

    const int a_r = tid >> 2;
    const int a_c = (tid & 3) << 2;
    const int b_r = tid >> 5;
    const int b_c = (tid & 31) << 2;

    float acc[8][8] = {};

    for (int k0 = 0; k0 < K; k0 += BK) {
        const float4 av0 = *(const float4*)&A[(size_t)(m0 + a_r) * K + k0 + a_c];
        const float4 av1 = *(const float4*)&A[(size_t)(m0 + a_r + 64) * K + k0 + a_c];
        const float4 bv0 = *(const float4*)&Bm[(size_t)(k0 + b_r) * N + n0 + b_c];
        const float4 bv1 = *(const float4*)&Bm[(size_t)(k0 + b_r + 8) * N + n0 + b_c];
        __syncthreads();
        As[a_c + 0][a_r] = av0.x;  As[a_c + 1][a_r] = av0.y;
        As[a_c + 2][a_r] = av0.z;  As[a_c + 3][a_r] = av0.w;
        As[a_c + 0][a_r + 64] = av1.x;  As[a_c + 1][a_r + 64] = av1.y;
        As[a_c + 2][a_r + 64] = av1.z;  As[a_c + 3][a_r + 64] = av1.w;
        *(float4*)&Bs[b_r][b_c] = bv0;
        *(float4*)&Bs[b_r + 8][b_c] = bv1;
        __syncthreads();

        #pragma unroll
        for (int kk = 0; kk < BK; ++kk) {
            float a[8], bf[8];
            *(float4*)&a[0]  = *(const float4*)&As[kk][tm];
            *(float4*)&a[4]  = *(const float4*)&As[kk][tm + 4];
            *(float4*)&bf[0] = *(const float4*)&Bs[kk][tn];
            *(float4*)&bf[4] = *(const float4*)&Bs[kk][tn + 4];
            #pragma unroll
            for (int i = 0; i < 8; ++i)
                #pragma unroll
                for (int jx = 0; jx < 8; ++jx)
                    acc[i][jx] += a[i] * bf[jx];
        }
    }

    float bv[8];
    #pragma unroll
    for (int jx = 0; jx < 8; ++jx) bv[jx] = bias[n0 + tn + jx];

    #pragma unroll
    for (int i = 0; i < 8; ++i) {
        float* crow = C + (size_t)(m0 + tm + i) * N + (n0 + tn);
        float4 o0, o1;
        o0.x = acc[i][0] + bv[0]; o0.y = acc[i][1] + bv[1];
        o0.z = acc[i][2] + bv[2]; o0.w = acc[i][3] + bv[3];
        o1.x = acc[i][4] + bv[4]; o1.y = acc[i][5] + bv[5];
        o1.z = acc[i][6] + bv[6]; o1.w = acc[i][7] + bv[7];
        *(float4*)&crow[0] = o0;
        *(float4*)&crow[4] = o1;
    }
}

// ---------------------------------------------------------------------------
// Persistent 2-layer pipelined LSTM. 128 WGs x 512 threads.
//   WGs 0..63  = layer 1: own h1-dims [8wg,8wg+8); weights Wh0 slice in regs.
//   WGs 64..127= layer 2: own h2-dims; Wh1 AND Wx1 slices in regs (xg2 on the fly).
// Comm buffers h1c/h2c are [t][dim][4batch] (16B/dim), memset to SENT each
// launch; every h word self-announces (no flags, one round-trip per step).
// c-state is register-resident in the 32 gate lanes of each WG.
// ---------------------------------------------------------------------------
__global__ __launch_bounds__(512, 1) void lstm2_kernel(
    const float* __restrict__ xg1, const float* __restrict__ Wh0,
    const float* __restrict__ Wx1, const float* __restrict__ Wh1,
    const float* __restrict__ b1,
    float* __restrict__ h1c, float* __restrict__ h2c,
    float* __restrict__ hs2)
{
    const int layer = blockIdx.x >> 6;
    const int wg    = blockIdx.x & 63;
    const int tid   = threadIdx.x;
    const int dbase = wg * 8;
    const int j = tid & 31;               // gate col within slice
    const int s = tid >> 5;               // row chunk 0..15 (also batch for tid<128)
    const int wcol = (j >> 3) * DIM + dbase + (j & 7);

    __shared__ f4v  hA[DIM];              // staged h (4 batches per dim)
    __shared__ f4v  hB[DIM];              // layer-2: h2[t-1]
    __shared__ float part[16][4][32];
    __shared__ float gate_lds[4][32];

    float wr[32], wx[32];
    {
        const float* Wrec = layer ? Wh1 : Wh0;
        #pragma unroll
        for (int r = 0; r < 32; ++r)
            wr[r] = Wrec[(size_t)(s * 32 + r) * GDIM + wcol];
        if (layer) {
            #pragma unroll
            for (int r = 0; r < 32; ++r)
                wx[r] = Wx1[(size_t)(s * 32 + r) * GDIM + wcol];
        }
    }
    float bias2 = 0.f;
    if (layer && tid < 128) bias2 = b1[wcol];

    float c_reg = 0.f;
    const unsigned* h1u = (const unsigned*)h1c;
    const unsigned* h2u = (const unsigned*)h2c;

    if (layer == 0) {
        for (int t = 0; t < TSEQ; ++t) {
            float xgv = 0.f;
            if (tid < 128) xgv = xg1[((size_t)s * TSEQ + t) * GDIM + wcol];

            if (t > 0) {
                const unsigned* p = h1u + ((size_t)(t - 1) * DIM + tid) * 4;
                uint4v u;
                do { u = poll_load16(p); }
                while (u.x == SENT || u.y == SENT || u.z == SENT || u.w == SENT);
                hA[tid] = __builtin_bit_cast(f4v, u);
            } else {
                hA[tid] = f4v{0.f, 0.f, 0.f, 0.f};
            }
            __syncthreads();

            float a0 = 0.f, a1 = 0.f, a2 = 0.f, a3 = 0.f;
            const f4v* hp = &hA[s * 32];
            #pragma unroll
            for (int r = 0; r < 32; ++r) {
                const f4v v = hp[r];
                a0 += v.x * wr[r]; a1 += v.y * wr[r];
                a2 += v.z * wr[r]; a3 += v.w * wr[r];
            }
            part[s][0][j] = a0; part[s][1][j] = a1;
            part[s][2][j] = a2; part[s][3][j] = a3;
            __syncthreads();

            if (tid < 128) {
                float sum = xgv;
                #pragma unroll
                for (int s2 = 0; s2 < 16; ++s2) sum += part[s2][s][j];
                gate_lds[s][j] = sum;
            }
            __syncthreads();

            if (tid < 32) {
                const int ub = tid >> 3, ud = tid & 7;
                const float iv = gate_lds[ub][ 0 + ud];
                const float fv = gate_lds[ub][ 8 + ud];
                const float gv = gate_lds[ub][16 + ud];
                const float ov = gate_lds[ub][24 + ud];
                const float ig = 1.f / (1.f + expf(-iv));
                const float fg = 1.f / (1.f + expf(-fv));
                const float og = 1.f / (1.f + expf(-ov));
                c_reg = fg * c_reg + ig * tanhf(gv);
                const float hval = og * tanhf(c_reg);
                __hip_atomic_store(&h1c[((size_t)t * DIM + dbase + ud) * 4 + ub], hval,
                                   __ATOMIC_RELAXED, __HIP_MEMORY_SCOPE_AGENT);
            }
        }
    } else {
        for (int t = 0; t < TSEQ; ++t) {
            // h2[t-1]: self-produced, ready early
            if (t > 0) {
                const unsigned* p = h2u + ((size_t)(t - 1) * DIM + tid) * 4;
                uint4v u;
                do { u = poll_load16(p); }
                while (u.x == SENT || u.y == SENT || u.z == SENT || u.w == SENT);
                hB[tid] = __builtin_bit_cast(f4v, u);
            } else {
                hB[tid] = f4v{0.f, 0.f, 0.f, 0.f};
            }
            __syncthreads();

            float a0 = 0.f, a1 = 0.f, a2 = 0.f, a3 = 0.f;
            {
                const f4v* hp = &hB[s * 32];
                #pragma unroll
                for (int r = 0; r < 32; ++r) {
                    const f4v v = hp[r];
                    a0 += v.x * wr[r]; a1 += v.y * wr[r];
                    a2 += v.z * wr[r]; a3 += v.w * wr[r];
                }
            }

            // h1[t]: produced concurrently by layer-1 (arrives late; Wh-MAC
            // above overlapped the wait)
            {
                const unsigned* p = h1u + ((size_t)t * DIM + tid) * 4;
                uint4v u;
                do { u = poll_load16(p); }
                while (u.x == SENT || u.y == SENT || u.z == SENT || u.w == SENT);
                hA[tid] = __builtin_bit_cast(f4v, u);
            }
            __syncthreads();
            {
                const f4v* hp = &hA[s * 32];
                #pragma unroll
                for (int r = 0; r < 32; ++r) {
                    const f4v v = hp[r];
                    a0 += v.x * wx[r]; a1 += v.y * wx[r];
                    a2 += v.z * wx[r]; a3 += v.w * wx[r];
                }
            }
            part[s][0][j] = a0; part[s][1][j] = a1;
            part[s][2][j] = a2; part[s][3][j] = a3;
            __syncthreads();

            if (tid < 128) {
                float sum = bias2;
                #pragma unroll
                for (int s2 = 0; s2 < 16; ++s2) sum += part[s2][s][j];
                gate_lds[s][j] = sum;
            }
            __syncthreads();

            if (tid < 32) {
                const int ub = tid >> 3, ud = tid & 7;
                const float iv = gate_lds[ub][ 0 + ud];
                const float fv = gate_lds[ub][ 8 + ud];
                const float gv = gate_lds[ub][16 + ud];
                const float ov = gate_lds[ub][24 + ud];
                const float ig = 1.f / (1.f + expf(-iv));
                const float fg = 1.f / (1.f + expf(-fv));
                const float og = 1.f / (1.f + expf(-ov));
                c_reg = fg * c_reg + ig * tanhf(gv);
                const float hval = og * tanhf(c_reg);
                __hip_atomic_store(&h2c[((size_t)t * DIM + dbase + ud) * 4 + ub], hval,
                                   __ATOMIC_RELAXED, __HIP_MEMORY_SCOPE_AGENT);
                // plain store for the logits GEMM (read next kernel, stream-ordered)
                hs2[((size_t)ub * TSEQ + t) * DIM + dbase + ud] = hval;
            }
        }
    }
}

// ---------------------------------------------------------------------------
extern "C" void kernel_launch(void* const* d_in, const int* in_sizes, int n_in,
                              void* d_out, int out_size, void* d_ws, size_t ws_size,
                              hipStream_t stream)
{
    const int*   tokens = (const int*)d_in[0];
    const float* embed  = (const float*)d_in[1];
    const float* Wx0    = (const float*)d_in[2];
    const float* Wh0    = (const float*)d_in[3];
    const float* b0     = (const float*)d_in[4];
    const float* Wx1    = (const float*)d_in[5];
    const float* Wh1    = (const float*)d_in[6];
    const float* b1     = (const float*)d_in[7];
    const float* Wout   = (const float*)d_in[8];
    const float* bout   = (const float*)d_in[9];
    float* out = (float*)d_out;

    char* ws = (char*)d_ws;
    float* x   = (float*)(ws);                      // reused as hs2 after GEMM1
    float* xg1 = (float*)(ws + ((size_t)8u << 20));
    float* h1c = (float*)(ws + ((size_t)40u << 20));
    float* h2c = (float*)(ws + ((size_t)48u << 20));
    float* hs2 = x;

    // sentinel-init both comm buffers (contiguous 16MB)
    hipMemsetAsync(ws + ((size_t)40u << 20), 0x7F, (size_t)16u << 20, stream);

    embed_kernel<<<dim3(4096), dim3(128), 0, stream>>>(tokens, embed, x);
    gemm_bias_f32<<<dim3(16, 32), dim3(256), 0, stream>>>(x, Wx0, b0, xg1, 4096, 2048, 512);
    lstm2_kernel<<<dim3(128), dim3(512), 0, stream>>>(xg1, Wh0, Wx1, Wh1, b1, h1c, h2c, hs2);
    gemm_bias_f32<<<dim3(250, 32), dim3(256), 0, stream>>>(hs2, Wout, bout, out, 4096, 32000, 512);
}